// Round 3
// baseline (293.742 us; speedup 1.0000x reference)
//
#include <hip/hip_runtime.h>
#include <hip/hip_bf16.h>
#include <cstdint>
#include <cstddef>

#define NB 4
#define CIN 256
#define CHID 128
#define HEADS 4
#define CHEAD 32
#define NPOS 4096      // 64*64
#define BH 16          // NB*HEADS
#define NTOT 16384     // NB*NPOS
#define QKV_O 384
// 32^-0.5 * log2(e): Q pre-scaled so softmax logits feed exp2 directly
#define QSCALE_LOG2E 0.2550348229f

typedef float f32x4 __attribute__((ext_vector_type(4)));
typedef short s16x8 __attribute__((ext_vector_type(8)));

static __device__ __forceinline__ unsigned short f2bf(float f) {
    union { float f; unsigned u; } v; v.f = f;
    unsigned r = v.u + 0x7FFFu + ((v.u >> 16) & 1u);
    return (unsigned short)(r >> 16);
}

static __device__ __forceinline__ unsigned int pk2bf(float a, float b) {
    union { __hip_bfloat162 h; unsigned int u; } c;
    c.h = __float22bfloat162_rn(float2{a, b});
    return c.u;
}

// ---------------- kernel 1: convert weights to bf16 ----------------
__global__ void k_convert_w(const float* __restrict__ wqkv, const float* __restrict__ wout,
                            unsigned short* __restrict__ wqkv_bf, unsigned short* __restrict__ wout_bf) {
    int i = blockIdx.x * 256 + threadIdx.x;
    if (i < QKV_O * CIN) wqkv_bf[i] = f2bf(wqkv[i]);
    if (i < CIN * CHID)  wout_bf[i]  = f2bf(wout[i]);
}

// ---------------- kernel 2: transpose x [b][256][4096] f32 -> xT [b*4096][256] bf16 ----------------
__global__ __launch_bounds__(256) void k_transpose_x(const float* __restrict__ x,
                                                     unsigned short* __restrict__ xT) {
    __shared__ float tile[32][33];
    const int ntiles = NPOS / 32;   // 128
    const int ctiles = CIN / 32;    // 8
    int b   = blockIdx.x / (ntiles * ctiles);
    int rem = blockIdx.x % (ntiles * ctiles);
    int ct = rem / ntiles;
    int nt = rem % ntiles;
    int c0 = ct * 32, n0 = nt * 32;
    int tc = threadIdx.x / 32;      // 0..7
    int tn = threadIdx.x % 32;
    const float* xb = x + (size_t)b * CIN * NPOS;
#pragma unroll
    for (int it = 0; it < 4; ++it) {
        int c = tc + it * 8;
        tile[c][tn] = xb[(size_t)(c0 + c) * NPOS + n0 + tn];
    }
    __syncthreads();
    unsigned short* xTb = xT + (size_t)b * NPOS * CIN;
#pragma unroll
    for (int it = 0; it < 4; ++it) {
        int n = tc + it * 8;
        xTb[(size_t)(n0 + n) * CIN + c0 + tn] = f2bf(tile[tn][n]);
    }
}

// ---------------- kernel 3: QKV projection GEMM (bf16 MFMA) ----------------
// C[o][nG] = sum_c wqkv[o][c] * xT[nG][c];  o<128 -> Q (scaled), o<256 -> K, else -> Vt
__global__ __launch_bounds__(256) void k_qkv(const unsigned short* __restrict__ wq,
                                             const unsigned short* __restrict__ xT,
                                             unsigned short* __restrict__ Q,
                                             unsigned short* __restrict__ K,
                                             unsigned short* __restrict__ V) {
    int mt = blockIdx.x % (QKV_O / 64);   // 0..5
    int nt = blockIdx.x / (QKV_O / 64);   // 0..255
    int wid = threadIdx.x >> 6, lane = threadIdx.x & 63;
    int quad = lane >> 4, low4 = lane & 15;
    int mw = mt * 64 + wid * 16;
    int n0 = nt * 64;
    f32x4 acc[4] = {};
    for (int k0 = 0; k0 < CIN; k0 += 32) {
        s16x8 a = *(const s16x8*)(wq + (size_t)(mw + low4) * CIN + k0 + quad * 8);
#pragma unroll
        for (int t = 0; t < 4; ++t) {
            s16x8 bfr = *(const s16x8*)(xT + (size_t)(n0 + t * 16 + low4) * CIN + k0 + quad * 8);
            acc[t] = __builtin_amdgcn_mfma_f32_16x16x32_bf16(a, bfr, acc[t], 0, 0, 0);
        }
    }
#pragma unroll
    for (int t = 0; t < 4; ++t) {
        int nG = n0 + t * 16 + low4;
        int b = nG >> 12, n = nG & 4095;
#pragma unroll
        for (int r = 0; r < 4; ++r) {
            int o = mw + quad * 4 + r;
            float v = acc[t][r];
            if (o < 128) {
                int head = o >> 5, ch = o & 31;
                Q[((size_t)(b * 4 + head) * NPOS + n) * 32 + ch] = f2bf(v * QSCALE_LOG2E);
            } else if (o < 256) {
                int o2 = o - 128; int head = o2 >> 5, ch = o2 & 31;
                K[((size_t)(b * 4 + head) * NPOS + n) * 32 + ch] = f2bf(v);
            } else {
                int o2 = o - 256; int head = o2 >> 5, ch = o2 & 31;
                V[((size_t)((b * 4 + head) * 32 + ch)) * NPOS + n] = f2bf(v);
            }
        }
    }
}

// ---------------- kernel 4: attention, S^T form + split-K in-block ----------------
// Grid: bh(16) x qtile(128, 32 queries each). Block: 4 waves.
//   wid&1  -> query group (16 queries), wid>>1 -> key half (2048 keys).
// Per wave: S^T = K·Q^T (C: col=query, row=key) -> per-lane scalar lsum ->
// packed b64 P^T writes to wave-private LDS -> 2x b128 B-frag reads ->
// O^T = Vt·P^T (C: col=query, row=ch). Key halves combined via LDS at end.
#define PROW 144   // P^T row stride in bytes (64 keys * 2B, padded; 16B-aligned)
__global__ __launch_bounds__(256) void k_attn(const unsigned short* __restrict__ Q,
                                              const unsigned short* __restrict__ K,
                                              const unsigned short* __restrict__ V,
                                              unsigned short* __restrict__ attnO) {
    __shared__ unsigned char pTraw[4][16 * PROW];   // 9216 B
    int bh = blockIdx.x >> 7;
    int qt = blockIdx.x & 127;
    int wid = threadIdx.x >> 6, lane = threadIdx.x & 63;
    int quad = lane >> 4, low4 = lane & 15;
    int qg = wid & 1, kh = wid >> 1;
    int q0 = qt * 32 + qg * 16;
    int kstart = kh * 2048, kend = kstart + 2048;

    const unsigned short* Qp = Q + (size_t)bh * NPOS * 32;
    const unsigned short* Kp = K + (size_t)bh * NPOS * 32 + low4 * 32 + quad * 8;
    const unsigned short* Vp = V + (size_t)bh * 32 * NPOS;
    const unsigned short* vrow0 = Vp + (size_t)low4 * NPOS + quad * 8;
    const unsigned short* vrow1 = Vp + (size_t)(low4 + 16) * NPOS + quad * 8;

    // B operand (n=query=low4, k=ch=quad*8+j)
    s16x8 bq = *(const s16x8*)(Qp + (size_t)(q0 + low4) * 32 + quad * 8);

    f32x4 oT0 = {}, oT1 = {};      // O^T ch-tiles 0..15, 16..31
    float lsum = 0.0f;

    unsigned char* myP = &pTraw[wid][0];
    unsigned char* wr = myP + low4 * PROW + 8 * quad;            // + 32*t
    const unsigned char* rd = myP + low4 * PROW + 16 * quad;     // + 64*g

    for (int k0 = kstart; k0 < kend; k0 += 64) {
        const unsigned short* kb = Kp + (size_t)k0 * 32;
        // A-frags for S^T: 4 key-tiles of 16
        s16x8 ak0 = *(const s16x8*)(kb);
        s16x8 ak1 = *(const s16x8*)(kb + 512);
        s16x8 ak2 = *(const s16x8*)(kb + 1024);
        s16x8 ak3 = *(const s16x8*)(kb + 1536);
        // A-frags for O^T: V^T, 2 ch-tiles x 2 key-groups
        s16x8 av00 = *(const s16x8*)(vrow0 + k0);
        s16x8 av01 = *(const s16x8*)(vrow0 + k0 + 32);
        s16x8 av10 = *(const s16x8*)(vrow1 + k0);
        s16x8 av11 = *(const s16x8*)(vrow1 + k0 + 32);

        f32x4 s0 = {}, s1 = {}, s2 = {}, s3 = {};
        s0 = __builtin_amdgcn_mfma_f32_16x16x32_bf16(ak0, bq, s0, 0, 0, 0);
        s1 = __builtin_amdgcn_mfma_f32_16x16x32_bf16(ak1, bq, s1, 0, 0, 0);
        s2 = __builtin_amdgcn_mfma_f32_16x16x32_bf16(ak2, bq, s2, 0, 0, 0);
        s3 = __builtin_amdgcn_mfma_f32_16x16x32_bf16(ak3, bq, s3, 0, 0, 0);

        // exp2 (log2e folded into Q), per-lane lsum, packed P^T writes
#pragma unroll
        for (int t = 0; t < 4; ++t) {
            f32x4 s = (t == 0) ? s0 : (t == 1) ? s1 : (t == 2) ? s2 : s3;
            float p0 = __builtin_amdgcn_exp2f(s[0]);
            float p1 = __builtin_amdgcn_exp2f(s[1]);
            float p2 = __builtin_amdgcn_exp2f(s[2]);
            float p3 = __builtin_amdgcn_exp2f(s[3]);
            lsum += (p0 + p1) + (p2 + p3);
            unsigned long long d = (unsigned long long)pk2bf(p0, p1)
                                 | ((unsigned long long)pk2bf(p2, p3) << 32);
            *(unsigned long long*)(wr + 32 * t) = d;
        }
        // B-frags of P^T (in-wave DS ordering: writes above precede these reads)
        s16x8 bp0 = *(const s16x8*)(rd);
        s16x8 bp1 = *(const s16x8*)(rd + 64);

        oT0 = __builtin_amdgcn_mfma_f32_16x16x32_bf16(av00, bp0, oT0, 0, 0, 0);
        oT1 = __builtin_amdgcn_mfma_f32_16x16x32_bf16(av10, bp0, oT1, 0, 0, 0);
        oT0 = __builtin_amdgcn_mfma_f32_16x16x32_bf16(av01, bp1, oT0, 0, 0, 0);
        oT1 = __builtin_amdgcn_mfma_f32_16x16x32_bf16(av11, bp1, oT1, 0, 0, 0);
    }

    // total lsum for this wave's key-half: reduce across quads (same low4=query)
    lsum += __shfl_xor(lsum, 16);
    lsum += __shfl_xor(lsum, 32);

    // combine key halves: waves 2,3 dump to their own P^T area; waves 0,1 merge
    if (kh) {
        float* dump = (float*)myP;
        dump[lane] = lsum;
#pragma unroll
        for (int i = 0; i < 4; ++i) {
            dump[64 + lane * 8 + i]     = oT0[i];
            dump[64 + lane * 8 + 4 + i] = oT1[i];
        }
    }
    __syncthreads();
    if (!kh) {
        const float* src = (const float*)&pTraw[wid + 2][0];
        lsum += src[lane];
        float inv = 1.0f / lsum;
        int b = bh >> 2, head = bh & 3;
        int n = q0 + low4;
        float o0[4], o1[4];
#pragma unroll
        for (int i = 0; i < 4; ++i) {
            o0[i] = (oT0[i] + src[64 + lane * 8 + i]) * inv;
            o1[i] = (oT1[i] + src[64 + lane * 8 + 4 + i]) * inv;
        }
        unsigned short* base = attnO + ((size_t)(b * NPOS + n)) * CHID + head * 32;
        *(unsigned long long*)(base + quad * 4) =
            (unsigned long long)pk2bf(o0[0], o0[1]) | ((unsigned long long)pk2bf(o0[2], o0[3]) << 32);
        *(unsigned long long*)(base + 16 + quad * 4) =
            (unsigned long long)pk2bf(o1[0], o1[1]) | ((unsigned long long)pk2bf(o1[2], o1[3]) << 32);
    }
}

// ---------------- kernel 5: output projection GEMM + bias ----------------
__global__ __launch_bounds__(256) void k_out(const unsigned short* __restrict__ wo,
                                             const unsigned short* __restrict__ attnO,
                                             const float* __restrict__ bias,
                                             float* __restrict__ out) {
    int mt = blockIdx.x & 3;        // 256/64
    int nt = blockIdx.x >> 2;       // 0..255
    int wid = threadIdx.x >> 6, lane = threadIdx.x & 63;
    int quad = lane >> 4, low4 = lane & 15;
    int mw = mt * 64 + wid * 16;
    int n0 = nt * 64;
    f32x4 acc[4] = {};
#pragma unroll
    for (int k0 = 0; k0 < CHID; k0 += 32) {
        s16x8 a = *(const s16x8*)(wo + (size_t)(mw + low4) * CHID + k0 + quad * 8);
#pragma unroll
        for (int t = 0; t < 4; ++t) {
            s16x8 bfr = *(const s16x8*)(attnO + (size_t)(n0 + t * 16 + low4) * CHID + k0 + quad * 8);
            acc[t] = __builtin_amdgcn_mfma_f32_16x16x32_bf16(a, bfr, acc[t], 0, 0, 0);
        }
    }
#pragma unroll
    for (int t = 0; t < 4; ++t) {
        int nG = n0 + t * 16 + low4;
        int b = nG >> 12, n = nG & 4095;
#pragma unroll
        for (int r = 0; r < 4; ++r) {
            int o = mw + quad * 4 + r;
            out[((size_t)(b * CIN + o)) * NPOS + n] = acc[t][r] + bias[o];
        }
    }
}

extern "C" void kernel_launch(void* const* d_in, const int* in_sizes, int n_in,
                              void* d_out, int out_size, void* d_ws, size_t ws_size,
                              hipStream_t stream) {
    const float* x    = (const float*)d_in[0];
    const float* wqkv = (const float*)d_in[1];
    const float* wout = (const float*)d_in[2];
    const float* bout = (const float*)d_in[3];
    float* out = (float*)d_out;

    unsigned short* Q       = (unsigned short*)d_ws;
    unsigned short* K       = Q + (size_t)BH * NPOS * 32;       // +4 MB
    unsigned short* V       = K + (size_t)BH * NPOS * 32;       // +4 MB
    unsigned short* attnO   = V + (size_t)BH * 32 * NPOS;       // +4 MB
    unsigned short* xT      = attnO + (size_t)NTOT * CHID;      // +4 MB
    unsigned short* wqkv_bf = xT + (size_t)NTOT * CIN;          // +8 MB
    unsigned short* wout_bf = wqkv_bf + QKV_O * CIN;            // +192 KB
    // total ~24.3 MB of ws

    k_convert_w<<<(QKV_O * CIN + 255) / 256, 256, 0, stream>>>(wqkv, wout, wqkv_bf, wout_bf);
    k_transpose_x<<<NB * (CIN / 32) * (NPOS / 32), 256, 0, stream>>>(x, xT);
    k_qkv<<<(QKV_O / 64) * (NTOT / 64), 256, 0, stream>>>(wqkv_bf, xT, Q, K, V);
    k_attn<<<BH * (NPOS / 32), 256, 0, stream>>>(Q, K, V, attnO);
    k_out<<<(CIN / 64) * (NTOT / 64), 256, 0, stream>>>(wout_bf, attnO, bout, out);
}

// Round 4
// 192.895 us; speedup vs baseline: 1.5228x; 1.5228x over previous
//
#include <hip/hip_runtime.h>
#include <hip/hip_bf16.h>
#include <cstdint>
#include <cstddef>

#define NB 4
#define CIN 256
#define CHID 128
#define HEADS 4
#define CHEAD 32
#define NPOS 4096      // 64*64
#define BH 16          // NB*HEADS
#define NTOT 16384     // NB*NPOS
#define QKV_O 384
// 32^-0.5 * log2(e): Q pre-scaled so softmax logits feed exp2 directly
#define QSCALE_LOG2E 0.2550348229f

typedef float f32x4 __attribute__((ext_vector_type(4)));
typedef short s16x8 __attribute__((ext_vector_type(8)));

static __device__ __forceinline__ unsigned short f2bf(float f) {
    union { float f; unsigned u; } v; v.f = f;
    unsigned r = v.u + 0x7FFFu + ((v.u >> 16) & 1u);
    return (unsigned short)(r >> 16);
}

static __device__ __forceinline__ unsigned int pk2bf(float a, float b) {
    union { __hip_bfloat162 h; unsigned int u; } c;
    c.h = __float22bfloat162_rn(float2{a, b});
    return c.u;
}

static __device__ __forceinline__ void async_cp16(const void* g, void* l) {
    __builtin_amdgcn_global_load_lds((const __attribute__((address_space(1))) unsigned int*)g,
                                     (__attribute__((address_space(3))) unsigned int*)l, 16, 0, 0);
}

// ---------------- kernel 1: convert weights to bf16 ----------------
__global__ void k_convert_w(const float* __restrict__ wqkv, const float* __restrict__ wout,
                            unsigned short* __restrict__ wqkv_bf, unsigned short* __restrict__ wout_bf) {
    int i = blockIdx.x * 256 + threadIdx.x;
    if (i < QKV_O * CIN) wqkv_bf[i] = f2bf(wqkv[i]);
    if (i < CIN * CHID)  wout_bf[i]  = f2bf(wout[i]);
}

// ---------------- kernel 2: transpose x [b][256][4096] f32 -> xT [b*4096][256] bf16 ----------------
__global__ __launch_bounds__(256) void k_transpose_x(const float* __restrict__ x,
                                                     unsigned short* __restrict__ xT) {
    __shared__ float tile[32][33];
    const int ntiles = NPOS / 32;   // 128
    const int ctiles = CIN / 32;    // 8
    int b   = blockIdx.x / (ntiles * ctiles);
    int rem = blockIdx.x % (ntiles * ctiles);
    int ct = rem / ntiles;
    int nt = rem % ntiles;
    int c0 = ct * 32, n0 = nt * 32;
    int tc = threadIdx.x / 32;      // 0..7
    int tn = threadIdx.x % 32;
    const float* xb = x + (size_t)b * CIN * NPOS;
#pragma unroll
    for (int it = 0; it < 4; ++it) {
        int c = tc + it * 8;
        tile[c][tn] = xb[(size_t)(c0 + c) * NPOS + n0 + tn];
    }
    __syncthreads();
    unsigned short* xTb = xT + (size_t)b * NPOS * CIN;
#pragma unroll
    for (int it = 0; it < 4; ++it) {
        int n = tc + it * 8;
        xTb[(size_t)(n0 + n) * CIN + c0 + tn] = f2bf(tile[tn][n]);
    }
}

// ---------------- kernel 3: QKV projection GEMM (bf16 MFMA) ----------------
__global__ __launch_bounds__(256) void k_qkv(const unsigned short* __restrict__ wq,
                                             const unsigned short* __restrict__ xT,
                                             unsigned short* __restrict__ Q,
                                             unsigned short* __restrict__ K,
                                             unsigned short* __restrict__ V) {
    int mt = blockIdx.x % (QKV_O / 64);   // 0..5
    int nt = blockIdx.x / (QKV_O / 64);   // 0..255
    int wid = threadIdx.x >> 6, lane = threadIdx.x & 63;
    int quad = lane >> 4, low4 = lane & 15;
    int mw = mt * 64 + wid * 16;
    int n0 = nt * 64;
    f32x4 acc[4] = {};
    for (int k0 = 0; k0 < CIN; k0 += 32) {
        s16x8 a = *(const s16x8*)(wq + (size_t)(mw + low4) * CIN + k0 + quad * 8);
#pragma unroll
        for (int t = 0; t < 4; ++t) {
            s16x8 bfr = *(const s16x8*)(xT + (size_t)(n0 + t * 16 + low4) * CIN + k0 + quad * 8);
            acc[t] = __builtin_amdgcn_mfma_f32_16x16x32_bf16(a, bfr, acc[t], 0, 0, 0);
        }
    }
    int o0 = mw + quad * 4;   // r = 0..3 contiguous, same 32-block -> same head
#pragma unroll
    for (int t = 0; t < 4; ++t) {
        int nG = n0 + t * 16 + low4;
        int b = nG >> 12, n = nG & 4095;
        if (o0 < 128) {
            int head = o0 >> 5, ch = o0 & 31;
            unsigned long long d =
                (unsigned long long)pk2bf(acc[t][0] * QSCALE_LOG2E, acc[t][1] * QSCALE_LOG2E) |
                ((unsigned long long)pk2bf(acc[t][2] * QSCALE_LOG2E, acc[t][3] * QSCALE_LOG2E) << 32);
            *(unsigned long long*)(Q + ((size_t)(b * 4 + head) * NPOS + n) * 32 + ch) = d;
        } else if (o0 < 256) {
            int o2 = o0 - 128; int head = o2 >> 5, ch = o2 & 31;
            unsigned long long d =
                (unsigned long long)pk2bf(acc[t][0], acc[t][1]) |
                ((unsigned long long)pk2bf(acc[t][2], acc[t][3]) << 32);
            *(unsigned long long*)(K + ((size_t)(b * 4 + head) * NPOS + n) * 32 + ch) = d;
        } else {
#pragma unroll
            for (int r = 0; r < 4; ++r) {
                int o2 = o0 + r - 256; int head = o2 >> 5, ch = o2 & 31;
                V[((size_t)((b * 4 + head) * 32 + ch)) * NPOS + n] = f2bf(acc[t][r]);
            }
        }
    }
}

// ---------------- kernel 4: attention, LDS-staged flash (m97 structure) ----------------
// Grid: bh(16) x qtile(32).  Block: 4 waves x 32 queries = 128 queries.
// Per 64-key tile: K(4KB)+V(4KB) staged once into double-buffered LDS via
// global_load_lds (8x 1KB, 2 per wave), consumed by all 4 waves.
// LDS images are in FRAGMENT ORDER: A-frag read addr = block + lane*16
// (canonical conflict-free b128). P^T also fragment-ordered: b64 packed
// writes (r contiguous), conflict-free b128 B-frag reads. Wave-private P^T
// needs no barrier (in-wave DS ordering).
__global__ __launch_bounds__(256, 2) void k_attn(const unsigned short* __restrict__ Q,
                                                 const unsigned short* __restrict__ K,
                                                 const unsigned short* __restrict__ V,
                                                 unsigned short* __restrict__ attnO) {
    __shared__ __align__(16) unsigned char smem[2 * 8192 + 4 * 4096];   // 32 KB
    unsigned char* kv = smem;            // [2][8192]: K tiles 0..3, V(c,g) 0..3, 1KB each
    unsigned char* pT = smem + 16384;    // [4 waves][4096]: (j*2+g) blocks of 1KB

    int bh  = blockIdx.x >> 5;
    int qt  = blockIdx.x & 31;
    int wid = threadIdx.x >> 6, lane = threadIdx.x & 63;
    int quad = lane >> 4, low4 = lane & 15;
    int l15 = low4, lhi = quad;
    int q0w = qt * 128 + wid * 32;

    const unsigned short* Qp = Q + (size_t)bh * NPOS * 32;
    const unsigned short* Kbh = K + (size_t)bh * NPOS * 32;
    const unsigned short* Vbh = V + (size_t)bh * 32 * NPOS;

    // staging sources (2x 1KB per wave per tile)
    const unsigned short* gs0;
    size_t sstep; int ldsA;
    if (wid < 2) {               // K tiles 2*wid, 2*wid+1: rows wid*32+l15, chunk lhi*8ch
        gs0 = Kbh + (size_t)(wid * 32 + l15) * 32 + lhi * 8;
        sstep = (size_t)64 * 32;
        ldsA = wid * 2048;
    } else {                     // V(c, g): rows c*16+l15, chunk g*32 + lhi*8 keys
        int c = wid - 2;
        gs0 = Vbh + (size_t)(c * 16 + l15) * NPOS + lhi * 8;
        sstep = 64;
        ldsA = 4096 + c * 2048;
    }
    const unsigned short* gs1 = gs0 + ((wid < 2) ? 512 : 32);

    // B operands (queries), held in registers for the whole kernel
    s16x8 bq0 = *(const s16x8*)(Qp + (size_t)(q0w + low4) * 32 + quad * 8);
    s16x8 bq1 = *(const s16x8*)(Qp + (size_t)(q0w + 16 + low4) * 32 + quad * 8);

    f32x4 o00 = {}, o01 = {}, o10 = {}, o11 = {};   // o[c][j]
    float lsum0 = 0.0f, lsum1 = 0.0f;

    unsigned char* pwave = pT + wid * 4096;
    unsigned char* pw = pwave + (quad >> 1) * 256 + low4 * 16 + (quad & 1) * 8;
    const int lby = lane * 16;

    // stage tile 0
    {
        unsigned char* dst = kv + ldsA;
        async_cp16(gs0, dst);
        async_cp16(gs1, dst + 1024);
    }
    __syncthreads();

    for (int it = 0; it < NPOS / 64; ++it) {
        if (it + 1 < NPOS / 64) {
            unsigned char* dst = kv + ((it + 1) & 1) * 8192 + ldsA;
            const unsigned short* s0 = gs0 + (size_t)(it + 1) * sstep;
            const unsigned short* s1 = gs1 + (size_t)(it + 1) * sstep;
            async_cp16(s0, dst);
            async_cp16(s1, dst + 1024);
        }
        const unsigned char* kb = kv + (it & 1) * 8192;
        s16x8 ak0  = *(const s16x8*)(kb + lby);
        s16x8 ak1  = *(const s16x8*)(kb + 1024 + lby);
        s16x8 ak2  = *(const s16x8*)(kb + 2048 + lby);
        s16x8 ak3  = *(const s16x8*)(kb + 3072 + lby);
        s16x8 av00 = *(const s16x8*)(kb + 4096 + lby);
        s16x8 av01 = *(const s16x8*)(kb + 5120 + lby);
        s16x8 av10 = *(const s16x8*)(kb + 6144 + lby);
        s16x8 av11 = *(const s16x8*)(kb + 7168 + lby);

        // S^T = K . Q^T : s[t][j], col=query(low4), row=key(quad*4+r)
        f32x4 s[4][2];
#pragma unroll
        for (int t = 0; t < 4; ++t) {
            s16x8 ak = (t == 0) ? ak0 : (t == 1) ? ak1 : (t == 2) ? ak2 : ak3;
            s[t][0] = __builtin_amdgcn_mfma_f32_16x16x32_bf16(ak, bq0, f32x4{}, 0, 0, 0);
            s[t][1] = __builtin_amdgcn_mfma_f32_16x16x32_bf16(ak, bq1, f32x4{}, 0, 0, 0);
        }

        // exp2 + pack into fragment-ordered P^T (b64 per (t,j))
#pragma unroll
        for (int t = 0; t < 4; ++t) {
#pragma unroll
            for (int j = 0; j < 2; ++j) {
                float p0 = __builtin_amdgcn_exp2f(s[t][j][0]);
                float p1 = __builtin_amdgcn_exp2f(s[t][j][1]);
                float p2 = __builtin_amdgcn_exp2f(s[t][j][2]);
                float p3 = __builtin_amdgcn_exp2f(s[t][j][3]);
                if (j == 0) lsum0 += (p0 + p1) + (p2 + p3);
                else        lsum1 += (p0 + p1) + (p2 + p3);
                unsigned long long d = (unsigned long long)pk2bf(p0, p1)
                                     | ((unsigned long long)pk2bf(p2, p3) << 32);
                *(unsigned long long*)(pw + j * 2048 + (t >> 1) * 1024 + (t & 1) * 512) = d;
            }
        }

        // B-frags of P^T (in-wave DS order guarantees visibility)
        s16x8 bp00 = *(const s16x8*)(pwave + lby);            // j=0,g=0
        s16x8 bp01 = *(const s16x8*)(pwave + 1024 + lby);     // j=0,g=1
        s16x8 bp10 = *(const s16x8*)(pwave + 2048 + lby);     // j=1,g=0
        s16x8 bp11 = *(const s16x8*)(pwave + 3072 + lby);     // j=1,g=1

        // O^T += V . P^T : o[c][j], col=query, row=ch(quad*4+r)
        o00 = __builtin_amdgcn_mfma_f32_16x16x32_bf16(av00, bp00, o00, 0, 0, 0);
        o01 = __builtin_amdgcn_mfma_f32_16x16x32_bf16(av00, bp10, o01, 0, 0, 0);
        o10 = __builtin_amdgcn_mfma_f32_16x16x32_bf16(av10, bp00, o10, 0, 0, 0);
        o11 = __builtin_amdgcn_mfma_f32_16x16x32_bf16(av10, bp10, o11, 0, 0, 0);
        o00 = __builtin_amdgcn_mfma_f32_16x16x32_bf16(av01, bp01, o00, 0, 0, 0);
        o01 = __builtin_amdgcn_mfma_f32_16x16x32_bf16(av01, bp11, o01, 0, 0, 0);
        o10 = __builtin_amdgcn_mfma_f32_16x16x32_bf16(av11, bp01, o10, 0, 0, 0);
        o11 = __builtin_amdgcn_mfma_f32_16x16x32_bf16(av11, bp11, o11, 0, 0, 0);

        __syncthreads();   // drains stage(it+1) vmcnt; protects kv buffers
    }

    // lsum: reduce across quads (keys) -> per-lane total for query low4
    lsum0 += __shfl_xor(lsum0, 16); lsum0 += __shfl_xor(lsum0, 32);
    lsum1 += __shfl_xor(lsum1, 16); lsum1 += __shfl_xor(lsum1, 32);
    float inv0 = 1.0f / lsum0, inv1 = 1.0f / lsum1;

    int b = bh >> 2, head = bh & 3;
#pragma unroll
    for (int c = 0; c < 2; ++c) {
#pragma unroll
        for (int j = 0; j < 2; ++j) {
            f32x4 o = (c == 0) ? (j == 0 ? o00 : o01) : (j == 0 ? o10 : o11);
            float inv = j == 0 ? inv0 : inv1;
            int n = q0w + j * 16 + low4;
            int ch = head * 32 + c * 16 + quad * 4;
            unsigned long long d =
                (unsigned long long)pk2bf(o[0] * inv, o[1] * inv) |
                ((unsigned long long)pk2bf(o[2] * inv, o[3] * inv) << 32);
            *(unsigned long long*)(attnO + ((size_t)(b * NPOS + n)) * CHID + ch) = d;
        }
    }
}

// ---------------- kernel 5: output projection GEMM + bias ----------------
__global__ __launch_bounds__(256) void k_out(const unsigned short* __restrict__ wo,
                                             const unsigned short* __restrict__ attnO,
                                             const float* __restrict__ bias,
                                             float* __restrict__ out) {
    int mt = blockIdx.x & 3;        // 256/64
    int nt = blockIdx.x >> 2;       // 0..255
    int wid = threadIdx.x >> 6, lane = threadIdx.x & 63;
    int quad = lane >> 4, low4 = lane & 15;
    int mw = mt * 64 + wid * 16;
    int n0 = nt * 64;
    f32x4 acc[4] = {};
#pragma unroll
    for (int k0 = 0; k0 < CHID; k0 += 32) {
        s16x8 a = *(const s16x8*)(wo + (size_t)(mw + low4) * CHID + k0 + quad * 8);
#pragma unroll
        for (int t = 0; t < 4; ++t) {
            s16x8 bfr = *(const s16x8*)(attnO + (size_t)(n0 + t * 16 + low4) * CHID + k0 + quad * 8);
            acc[t] = __builtin_amdgcn_mfma_f32_16x16x32_bf16(a, bfr, acc[t], 0, 0, 0);
        }
    }
#pragma unroll
    for (int t = 0; t < 4; ++t) {
        int nG = n0 + t * 16 + low4;
        int b = nG >> 12, n = nG & 4095;
#pragma unroll
        for (int r = 0; r < 4; ++r) {
            int o = mw + quad * 4 + r;
            out[((size_t)(b * CIN + o)) * NPOS + n] = acc[t][r] + bias[o];
        }
    }
}

extern "C" void kernel_launch(void* const* d_in, const int* in_sizes, int n_in,
                              void* d_out, int out_size, void* d_ws, size_t ws_size,
                              hipStream_t stream) {
    const float* x    = (const float*)d_in[0];
    const float* wqkv = (const float*)d_in[1];
    const float* wout = (const float*)d_in[2];
    const float* bout = (const float*)d_in[3];
    float* out = (float*)d_out;

    unsigned short* Q       = (unsigned short*)d_ws;
    unsigned short* K       = Q + (size_t)BH * NPOS * 32;       // +4 MB
    unsigned short* V       = K + (size_t)BH * NPOS * 32;       // +4 MB
    unsigned short* attnO   = V + (size_t)BH * 32 * NPOS;       // +4 MB
    unsigned short* xT      = attnO + (size_t)NTOT * CHID;      // +4 MB
    unsigned short* wqkv_bf = xT + (size_t)NTOT * CIN;          // +8 MB
    unsigned short* wout_bf = wqkv_bf + QKV_O * CIN;            // +192 KB

    k_convert_w<<<(QKV_O * CIN + 255) / 256, 256, 0, stream>>>(wqkv, wout, wqkv_bf, wout_bf);
    k_transpose_x<<<NB * (CIN / 32) * (NPOS / 32), 256, 0, stream>>>(x, xT);
    k_qkv<<<(QKV_O / 64) * (NTOT / 64), 256, 0, stream>>>(wqkv_bf, xT, Q, K, V);
    k_attn<<<BH * (NPOS / 128), 256, 0, stream>>>(Q, K, V, attnO);
    k_out<<<(CIN / 64) * (NTOT / 64), 256, 0, stream>>>(wout_bf, attnO, bout, out);
}

// Round 5
// 164.056 us; speedup vs baseline: 1.7905x; 1.1758x over previous
//
#include <hip/hip_runtime.h>
#include <hip/hip_bf16.h>
#include <cstdint>
#include <cstddef>

#define NB 4
#define CIN 256
#define CHID 128
#define HEADS 4
#define CHEAD 32
#define NPOS 4096      // 64*64
#define BH 16          // NB*HEADS
#define NTOT 16384     // NB*NPOS
#define QKV_O 384
// 32^-0.5 * log2(e): Q pre-scaled so softmax logits feed exp2 directly
#define QSCALE_LOG2E 0.2550348229f

typedef float f32x4 __attribute__((ext_vector_type(4)));
typedef short s16x8 __attribute__((ext_vector_type(8)));

static __device__ __forceinline__ unsigned short f2bf(float f) {
    union { float f; unsigned u; } v; v.f = f;
    unsigned r = v.u + 0x7FFFu + ((v.u >> 16) & 1u);
    return (unsigned short)(r >> 16);
}

static __device__ __forceinline__ unsigned int pk2bf(float a, float b) {
    union { __hip_bfloat162 h; unsigned int u; } c;
    c.h = __float22bfloat162_rn(float2{a, b});
    return c.u;
}

static __device__ __forceinline__ void async_cp16(const void* g, void* l) {
    __builtin_amdgcn_global_load_lds((const __attribute__((address_space(1))) unsigned int*)g,
                                     (__attribute__((address_space(3))) unsigned int*)l, 16, 0, 0);
}

// ---------------- kernel 1: convert weights to bf16 ----------------
__global__ void k_convert_w(const float* __restrict__ wqkv, const float* __restrict__ wout,
                            unsigned short* __restrict__ wqkv_bf, unsigned short* __restrict__ wout_bf) {
    int i = blockIdx.x * 256 + threadIdx.x;
    if (i < QKV_O * CIN) wqkv_bf[i] = f2bf(wqkv[i]);
    if (i < CIN * CHID)  wout_bf[i]  = f2bf(wout[i]);
}

// ---------------- kernel 2: transpose x [b][256][4096] f32 -> xT [b*4096][256] bf16 ----------------
__global__ __launch_bounds__(256) void k_transpose_x(const float* __restrict__ x,
                                                     unsigned short* __restrict__ xT) {
    __shared__ float tile[32][33];
    const int ntiles = NPOS / 32;   // 128
    const int ctiles = CIN / 32;    // 8
    int b   = blockIdx.x / (ntiles * ctiles);
    int rem = blockIdx.x % (ntiles * ctiles);
    int ct = rem / ntiles;
    int nt = rem % ntiles;
    int c0 = ct * 32, n0 = nt * 32;
    int tc = threadIdx.x / 32;      // 0..7
    int tn = threadIdx.x % 32;
    const float* xb = x + (size_t)b * CIN * NPOS;
#pragma unroll
    for (int it = 0; it < 4; ++it) {
        int c = tc + it * 8;
        tile[c][tn] = xb[(size_t)(c0 + c) * NPOS + n0 + tn];
    }
    __syncthreads();
    unsigned short* xTb = xT + (size_t)b * NPOS * CIN;
#pragma unroll
    for (int it = 0; it < 4; ++it) {
        int n = tc + it * 8;
        xTb[(size_t)(n0 + n) * CIN + c0 + tn] = f2bf(tile[tn][n]);
    }
}

// ---------------- kernel 3: QKV projection GEMM, LDS-staged (m97 structure) ----------------
// Tile 128(o) x 64(n), K=256 in 8 chunks of 32. Grid 3 x 256 = 768 (3 blocks/CU).
// Per chunk: A=wq 128x32 (8KB, frag-ordered subtiles) + B=xT 64x32 (4KB), dbuf.
__global__ __launch_bounds__(256, 4) void k_qkv(const unsigned short* __restrict__ wq,
                                                const unsigned short* __restrict__ xT,
                                                unsigned short* __restrict__ Q,
                                                unsigned short* __restrict__ K,
                                                unsigned short* __restrict__ V) {
    __shared__ __align__(16) unsigned char smem[2 * 12288];   // 24 KB
    int mt = blockIdx.x % 3;
    int nt = blockIdx.x / 3;
    int wid = threadIdx.x >> 6, lane = threadIdx.x & 63;
    int quad = lane >> 4, low4 = lane & 15;
    int o0 = mt * 128, n0 = nt * 64;
    int lb = lane * 16;

    const unsigned short* srcA0 = wq + (size_t)(o0 + wid * 32 + low4) * CIN + quad * 8;
    const unsigned short* srcA1 = srcA0 + 16 * CIN;
    const unsigned short* srcB  = xT + (size_t)(n0 + wid * 16 + low4) * CIN + quad * 8;
    int dA0 = wid * 2048, dA1 = dA0 + 1024, dB = 8192 + wid * 1024;

    async_cp16(srcA0, smem + dA0 + lb);
    async_cp16(srcA1, smem + dA1 + lb);
    async_cp16(srcB,  smem + dB  + lb);
    __syncthreads();

    f32x4 acc[2][4] = {};
    for (int c = 0; c < 8; ++c) {
        if (c < 7) {
            unsigned char* nxt = smem + ((c + 1) & 1) * 12288;
            async_cp16(srcA0 + (c + 1) * 32, nxt + dA0 + lb);
            async_cp16(srcA1 + (c + 1) * 32, nxt + dA1 + lb);
            async_cp16(srcB  + (c + 1) * 32, nxt + dB  + lb);
        }
        const unsigned char* cur = smem + (c & 1) * 12288;
        s16x8 a0 = *(const s16x8*)(cur + wid * 2048 + lb);
        s16x8 a1 = *(const s16x8*)(cur + wid * 2048 + 1024 + lb);
#pragma unroll
        for (int j = 0; j < 4; ++j) {
            s16x8 bj = *(const s16x8*)(cur + 8192 + j * 1024 + lb);
            acc[0][j] = __builtin_amdgcn_mfma_f32_16x16x32_bf16(a0, bj, acc[0][j], 0, 0, 0);
            acc[1][j] = __builtin_amdgcn_mfma_f32_16x16x32_bf16(a1, bj, acc[1][j], 0, 0, 0);
        }
        __syncthreads();
    }

#pragma unroll
    for (int i = 0; i < 2; ++i) {
        int ob = o0 + wid * 32 + i * 16 + quad * 4;   // 4 consecutive outs, same head
#pragma unroll
        for (int j = 0; j < 4; ++j) {
            int nG = n0 + j * 16 + low4;
            int b = nG >> 12, n = nG & 4095;
            f32x4 v = acc[i][j];
            if (ob < 128) {
                int head = ob >> 5, ch = ob & 31;
                unsigned long long d =
                    (unsigned long long)pk2bf(v[0] * QSCALE_LOG2E, v[1] * QSCALE_LOG2E) |
                    ((unsigned long long)pk2bf(v[2] * QSCALE_LOG2E, v[3] * QSCALE_LOG2E) << 32);
                *(unsigned long long*)(Q + ((size_t)(b * 4 + head) * NPOS + n) * 32 + ch) = d;
            } else if (ob < 256) {
                int o2 = ob - 128; int head = o2 >> 5, ch = o2 & 31;
                unsigned long long d =
                    (unsigned long long)pk2bf(v[0], v[1]) |
                    ((unsigned long long)pk2bf(v[2], v[3]) << 32);
                *(unsigned long long*)(K + ((size_t)(b * 4 + head) * NPOS + n) * 32 + ch) = d;
            } else {
#pragma unroll
                for (int r = 0; r < 4; ++r) {
                    int o2 = ob + r - 256; int head = o2 >> 5, ch = o2 & 31;
                    V[((size_t)((b * 4 + head) * 32 + ch)) * NPOS + n] = f2bf(v[r]);
                }
            }
        }
    }
}

// ---------------- kernel 4: attention, LDS-staged flash, 64 q/block ----------------
// Grid: bh(16) x qtile(64). Block: 4 waves x 16 queries. 4 blocks/CU (vs 2 in R4).
// Per 64-key tile: K(4KB)+V(4KB) dbuf-staged via global_load_lds, shared by waves.
__global__ __launch_bounds__(256, 4) void k_attn(const unsigned short* __restrict__ Q,
                                                 const unsigned short* __restrict__ K,
                                                 const unsigned short* __restrict__ V,
                                                 unsigned short* __restrict__ attnO) {
    __shared__ __align__(16) unsigned char smem[2 * 8192 + 4 * 2048];   // 24 KB
    unsigned char* kv = smem;            // [2][8192]: K subtiles 0..3 (1KB), V[c][g] (1KB)
    unsigned char* pT = smem + 16384;    // [4 waves][2048]: P^T, [g][kq][q][8k]

    int bh  = blockIdx.x >> 6;
    int qt  = blockIdx.x & 63;
    int wid = threadIdx.x >> 6, lane = threadIdx.x & 63;
    int quad = lane >> 4, low4 = lane & 15;
    int q0w = qt * 64 + wid * 16;

    const unsigned short* Qp  = Q + (size_t)bh * NPOS * 32;
    const unsigned short* Kbh = K + (size_t)bh * NPOS * 32;
    const unsigned short* Vbh = V + (size_t)bh * 32 * NPOS;

    const unsigned short* gs0;
    size_t sstep; int ldsA;
    if (wid < 2) {               // K subtiles 2*wid, 2*wid+1
        gs0 = Kbh + (size_t)(wid * 32 + low4) * 32 + quad * 8;
        sstep = (size_t)64 * 32;
        ldsA = wid * 2048;
    } else {                     // V ch-subtile c, key-groups 0,1
        int c = wid - 2;
        gs0 = Vbh + (size_t)(c * 16 + low4) * NPOS + quad * 8;
        sstep = 64;
        ldsA = 4096 + c * 2048;
    }
    const unsigned short* gs1 = gs0 + ((wid < 2) ? 512 : 32);

    s16x8 bq = *(const s16x8*)(Qp + (size_t)(q0w + low4) * 32 + quad * 8);

    f32x4 oc0 = {}, oc1 = {};    // ch 0..15, 16..31 (col=query, row=ch)
    float lsum = 0.0f;

    unsigned char* pwave = pT + wid * 2048;
    unsigned char* pw = pwave + (quad >> 1) * 256 + low4 * 16 + (quad & 1) * 8;
    const int lby = lane * 16;

    async_cp16(gs0, kv + ldsA);
    async_cp16(gs1, kv + ldsA + 1024);
    __syncthreads();

    for (int it = 0; it < NPOS / 64; ++it) {
        if (it + 1 < NPOS / 64) {
            unsigned char* dst = kv + ((it + 1) & 1) * 8192 + ldsA;
            async_cp16(gs0 + (size_t)(it + 1) * sstep, dst);
            async_cp16(gs1 + (size_t)(it + 1) * sstep, dst + 1024);
        }
        const unsigned char* kb = kv + (it & 1) * 8192;
        s16x8 ak0  = *(const s16x8*)(kb + lby);
        s16x8 ak1  = *(const s16x8*)(kb + 1024 + lby);
        s16x8 ak2  = *(const s16x8*)(kb + 2048 + lby);
        s16x8 ak3  = *(const s16x8*)(kb + 3072 + lby);
        s16x8 av00 = *(const s16x8*)(kb + 4096 + lby);   // c=0,g=0
        s16x8 av01 = *(const s16x8*)(kb + 5120 + lby);   // c=0,g=1
        s16x8 av10 = *(const s16x8*)(kb + 6144 + lby);   // c=1,g=0
        s16x8 av11 = *(const s16x8*)(kb + 7168 + lby);   // c=1,g=1

        // S^T = K . Q^T (col=query low4, row=key quad*4+r within subtile t)
        f32x4 s[4];
        s[0] = __builtin_amdgcn_mfma_f32_16x16x32_bf16(ak0, bq, f32x4{}, 0, 0, 0);
        s[1] = __builtin_amdgcn_mfma_f32_16x16x32_bf16(ak1, bq, f32x4{}, 0, 0, 0);
        s[2] = __builtin_amdgcn_mfma_f32_16x16x32_bf16(ak2, bq, f32x4{}, 0, 0, 0);
        s[3] = __builtin_amdgcn_mfma_f32_16x16x32_bf16(ak3, bq, f32x4{}, 0, 0, 0);

        // exp2 + packed b64 P^T writes (fragment-ordered, wave-private)
#pragma unroll
        for (int t = 0; t < 4; ++t) {
            float p0 = __builtin_amdgcn_exp2f(s[t][0]);
            float p1 = __builtin_amdgcn_exp2f(s[t][1]);
            float p2 = __builtin_amdgcn_exp2f(s[t][2]);
            float p3 = __builtin_amdgcn_exp2f(s[t][3]);
            lsum += (p0 + p1) + (p2 + p3);
            unsigned long long d = (unsigned long long)pk2bf(p0, p1)
                                 | ((unsigned long long)pk2bf(p2, p3) << 32);
            *(unsigned long long*)(pw + (t >> 1) * 1024 + (t & 1) * 512) = d;
        }
        // B-frags of P^T (in-wave DS ordering)
        s16x8 bp0 = *(const s16x8*)(pwave + lby);
        s16x8 bp1 = *(const s16x8*)(pwave + 1024 + lby);

        // O^T += V . P^T
        oc0 = __builtin_amdgcn_mfma_f32_16x16x32_bf16(av00, bp0, oc0, 0, 0, 0);
        oc1 = __builtin_amdgcn_mfma_f32_16x16x32_bf16(av10, bp0, oc1, 0, 0, 0);
        oc0 = __builtin_amdgcn_mfma_f32_16x16x32_bf16(av01, bp1, oc0, 0, 0, 0);
        oc1 = __builtin_amdgcn_mfma_f32_16x16x32_bf16(av11, bp1, oc1, 0, 0, 0);

        __syncthreads();   // drains stage(it+1); protects kv dbuf
    }

    lsum += __shfl_xor(lsum, 16);
    lsum += __shfl_xor(lsum, 32);
    float inv = 1.0f / lsum;

    int b = bh >> 2, head = bh & 3;
    int n = q0w + low4;
#pragma unroll
    for (int c = 0; c < 2; ++c) {
        f32x4 o = c == 0 ? oc0 : oc1;
        int ch = head * 32 + c * 16 + quad * 4;
        unsigned long long d =
            (unsigned long long)pk2bf(o[0] * inv, o[1] * inv) |
            ((unsigned long long)pk2bf(o[2] * inv, o[3] * inv) << 32);
        *(unsigned long long*)(attnO + ((size_t)(b * NPOS + n)) * CHID + ch) = d;
    }
}

// ---------------- kernel 5: output projection GEMM + bias, LDS-staged ----------------
// Tile 128(o) x 64(n), K=128 in 4 chunks. Grid 2 x 256 = 512.
__global__ __launch_bounds__(256, 4) void k_out(const unsigned short* __restrict__ wo,
                                                const unsigned short* __restrict__ attnO,
                                                const float* __restrict__ bias,
                                                float* __restrict__ out) {
    __shared__ __align__(16) unsigned char smem[2 * 12288];   // 24 KB
    int mt = blockIdx.x & 1;
    int nt = blockIdx.x >> 1;
    int wid = threadIdx.x >> 6, lane = threadIdx.x & 63;
    int quad = lane >> 4, low4 = lane & 15;
    int o0 = mt * 128, n0 = nt * 64;
    int lb = lane * 16;

    const unsigned short* srcA0 = wo + (size_t)(o0 + wid * 32 + low4) * CHID + quad * 8;
    const unsigned short* srcA1 = srcA0 + 16 * CHID;
    const unsigned short* srcB  = attnO + (size_t)(n0 + wid * 16 + low4) * CHID + quad * 8;
    int dA0 = wid * 2048, dA1 = dA0 + 1024, dB = 8192 + wid * 1024;

    async_cp16(srcA0, smem + dA0 + lb);
    async_cp16(srcA1, smem + dA1 + lb);
    async_cp16(srcB,  smem + dB  + lb);
    __syncthreads();

    f32x4 acc[2][4] = {};
    for (int c = 0; c < 4; ++c) {
        if (c < 3) {
            unsigned char* nxt = smem + ((c + 1) & 1) * 12288;
            async_cp16(srcA0 + (c + 1) * 32, nxt + dA0 + lb);
            async_cp16(srcA1 + (c + 1) * 32, nxt + dA1 + lb);
            async_cp16(srcB  + (c + 1) * 32, nxt + dB  + lb);
        }
        const unsigned char* cur = smem + (c & 1) * 12288;
        s16x8 a0 = *(const s16x8*)(cur + wid * 2048 + lb);
        s16x8 a1 = *(const s16x8*)(cur + wid * 2048 + 1024 + lb);
#pragma unroll
        for (int j = 0; j < 4; ++j) {
            s16x8 bj = *(const s16x8*)(cur + 8192 + j * 1024 + lb);
            acc[0][j] = __builtin_amdgcn_mfma_f32_16x16x32_bf16(a0, bj, acc[0][j], 0, 0, 0);
            acc[1][j] = __builtin_amdgcn_mfma_f32_16x16x32_bf16(a1, bj, acc[1][j], 0, 0, 0);
        }
        __syncthreads();
    }

#pragma unroll
    for (int i = 0; i < 2; ++i) {
        int ob = o0 + wid * 32 + i * 16 + quad * 4;
#pragma unroll
        for (int j = 0; j < 4; ++j) {
            int nG = n0 + j * 16 + low4;
            int b = nG >> 12, n = nG & 4095;
#pragma unroll
            for (int r = 0; r < 4; ++r) {
                int o = ob + r;
                out[((size_t)(b * CIN + o)) * NPOS + n] = acc[i][j][r] + bias[o];
            }
        }
    }
}

extern "C" void kernel_launch(void* const* d_in, const int* in_sizes, int n_in,
                              void* d_out, int out_size, void* d_ws, size_t ws_size,
                              hipStream_t stream) {
    const float* x    = (const float*)d_in[0];
    const float* wqkv = (const float*)d_in[1];
    const float* wout = (const float*)d_in[2];
    const float* bout = (const float*)d_in[3];
    float* out = (float*)d_out;

    unsigned short* Q       = (unsigned short*)d_ws;
    unsigned short* K       = Q + (size_t)BH * NPOS * 32;       // +4 MB
    unsigned short* V       = K + (size_t)BH * NPOS * 32;       // +4 MB
    unsigned short* attnO   = V + (size_t)BH * 32 * NPOS;       // +4 MB
    unsigned short* xT      = attnO + (size_t)NTOT * CHID;      // +4 MB
    unsigned short* wqkv_bf = xT + (size_t)NTOT * CIN;          // +8 MB
    unsigned short* wout_bf = wqkv_bf + QKV_O * CIN;            // +192 KB

    k_convert_w<<<(QKV_O * CIN + 255) / 256, 256, 0, stream>>>(wqkv, wout, wqkv_bf, wout_bf);
    k_transpose_x<<<NB * (CIN / 32) * (NPOS / 32), 256, 0, stream>>>(x, xT);
    k_qkv<<<3 * (NTOT / 64), 256, 0, stream>>>(wqkv_bf, xT, Q, K, V);
    k_attn<<<BH * (NPOS / 64), 256, 0, stream>>>(Q, K, V, attnO);
    k_out<<<2 * (NTOT / 64), 256, 0, stream>>>(wout_bf, attnO, bout, out);
}

// Round 6
// 153.622 us; speedup vs baseline: 1.9121x; 1.0679x over previous
//
#include <hip/hip_runtime.h>
#include <hip/hip_bf16.h>
#include <cstdint>
#include <cstddef>

#define NB 4
#define CIN 256
#define CHID 128
#define HEADS 4
#define CHEAD 32
#define NPOS 4096      // 64*64
#define BH 16          // NB*HEADS
#define NTOT 16384     // NB*NPOS
#define QKV_O 384
// 32^-0.5 * log2(e): Q pre-scaled so softmax logits feed exp2 directly
#define QSCALE_LOG2E 0.2550348229f

typedef float f32x4 __attribute__((ext_vector_type(4)));
typedef float f32x16 __attribute__((ext_vector_type(16)));
typedef short s16x8 __attribute__((ext_vector_type(8)));

static __device__ __forceinline__ unsigned short f2bf(float f) {
    union { float f; unsigned u; } v; v.f = f;
    unsigned r = v.u + 0x7FFFu + ((v.u >> 16) & 1u);
    return (unsigned short)(r >> 16);
}

static __device__ __forceinline__ unsigned int pk2bf(float a, float b) {
    union { __hip_bfloat162 h; unsigned int u; } c;
    c.h = __float22bfloat162_rn(float2{a, b});
    return c.u;
}

// Exchange upper-half lanes of a with lower-half lanes of b (gfx950 VALU op).
// Post: a = {a.lo | b.lo}, b = {a.hi | b.hi}  (per-lane across the 32-lane halves)
static __device__ __forceinline__ void plswap(unsigned& a, unsigned& b) {
#if __has_builtin(__builtin_amdgcn_permlane32_swap)
    auto r = __builtin_amdgcn_permlane32_swap((int)a, (int)b, false, false);
    a = (unsigned)r[0];
    b = (unsigned)r[1];
#else
    int hh = (threadIdx.x >> 5) & 1;
    unsigned ta = (unsigned)__shfl_xor((int)a, 32);
    unsigned tb = (unsigned)__shfl_xor((int)b, 32);
    unsigned na = hh ? tb : a;
    unsigned nb = hh ? b : ta;
    a = na; b = nb;
#endif
}

static __device__ __forceinline__ s16x8 mk8(unsigned a, unsigned b, unsigned c, unsigned d) {
    union { unsigned u[4]; s16x8 v; } x;
    x.u[0] = a; x.u[1] = b; x.u[2] = c; x.u[3] = d;
    return x.v;
}

static __device__ __forceinline__ void async_cp16(const void* g, void* l) {
    __builtin_amdgcn_global_load_lds((const __attribute__((address_space(1))) unsigned int*)g,
                                     (__attribute__((address_space(3))) unsigned int*)l, 16, 0, 0);
}

#define MFMA32(a, b, c) __builtin_amdgcn_mfma_f32_32x32x16_bf16(a, b, c, 0, 0, 0)

// ---------------- kernel 1: convert weights to bf16 ----------------
__global__ void k_convert_w(const float* __restrict__ wqkv, const float* __restrict__ wout,
                            unsigned short* __restrict__ wqkv_bf, unsigned short* __restrict__ wout_bf) {
    int i = blockIdx.x * 256 + threadIdx.x;
    if (i < QKV_O * CIN) wqkv_bf[i] = f2bf(wqkv[i]);
    if (i < CIN * CHID)  wout_bf[i]  = f2bf(wout[i]);
}

// ---------------- kernel 2: transpose x [b][256][4096] f32 -> xT [b*4096][256] bf16 ----------------
__global__ __launch_bounds__(256) void k_transpose_x(const float* __restrict__ x,
                                                     unsigned short* __restrict__ xT) {
    __shared__ float tile[32][33];
    const int ntiles = NPOS / 32;   // 128
    const int ctiles = CIN / 32;    // 8
    int b   = blockIdx.x / (ntiles * ctiles);
    int rem = blockIdx.x % (ntiles * ctiles);
    int ct = rem / ntiles;
    int nt = rem % ntiles;
    int c0 = ct * 32, n0 = nt * 32;
    int tc = threadIdx.x / 32;      // 0..7
    int tn = threadIdx.x % 32;
    const float* xb = x + (size_t)b * CIN * NPOS;
#pragma unroll
    for (int it = 0; it < 4; ++it) {
        int c = tc + it * 8;
        tile[c][tn] = xb[(size_t)(c0 + c) * NPOS + n0 + tn];
    }
    __syncthreads();
    unsigned short* xTb = xT + (size_t)b * NPOS * CIN;
#pragma unroll
    for (int it = 0; it < 4; ++it) {
        int n = tc + it * 8;
        xTb[(size_t)(n0 + n) * CIN + c0 + tn] = f2bf(tile[tn][n]);
    }
}

// ---------------- kernel 3: QKV projection GEMM, LDS-staged ----------------
__global__ __launch_bounds__(256, 4) void k_qkv(const unsigned short* __restrict__ wq,
                                                const unsigned short* __restrict__ xT,
                                                unsigned short* __restrict__ Q,
                                                unsigned short* __restrict__ K,
                                                unsigned short* __restrict__ V) {
    __shared__ __align__(16) unsigned char smem[2 * 12288];   // 24 KB
    int mt = blockIdx.x % 3;
    int nt = blockIdx.x / 3;
    int wid = threadIdx.x >> 6, lane = threadIdx.x & 63;
    int quad = lane >> 4, low4 = lane & 15;
    int o0 = mt * 128, n0 = nt * 64;
    int lb = lane * 16;

    const unsigned short* srcA0 = wq + (size_t)(o0 + wid * 32 + low4) * CIN + quad * 8;
    const unsigned short* srcA1 = srcA0 + 16 * CIN;
    const unsigned short* srcB  = xT + (size_t)(n0 + wid * 16 + low4) * CIN + quad * 8;
    int dA0 = wid * 2048, dA1 = dA0 + 1024, dB = 8192 + wid * 1024;

    async_cp16(srcA0, smem + dA0 + lb);
    async_cp16(srcA1, smem + dA1 + lb);
    async_cp16(srcB,  smem + dB  + lb);
    __syncthreads();

    f32x4 acc[2][4] = {};
    for (int c = 0; c < 8; ++c) {
        if (c < 7) {
            unsigned char* nxt = smem + ((c + 1) & 1) * 12288;
            async_cp16(srcA0 + (c + 1) * 32, nxt + dA0 + lb);
            async_cp16(srcA1 + (c + 1) * 32, nxt + dA1 + lb);
            async_cp16(srcB  + (c + 1) * 32, nxt + dB  + lb);
        }
        const unsigned char* cur = smem + (c & 1) * 12288;
        s16x8 a0 = *(const s16x8*)(cur + wid * 2048 + lb);
        s16x8 a1 = *(const s16x8*)(cur + wid * 2048 + 1024 + lb);
#pragma unroll
        for (int j = 0; j < 4; ++j) {
            s16x8 bj = *(const s16x8*)(cur + 8192 + j * 1024 + lb);
            acc[0][j] = __builtin_amdgcn_mfma_f32_16x16x32_bf16(a0, bj, acc[0][j], 0, 0, 0);
            acc[1][j] = __builtin_amdgcn_mfma_f32_16x16x32_bf16(a1, bj, acc[1][j], 0, 0, 0);
        }
        __syncthreads();
    }

#pragma unroll
    for (int i = 0; i < 2; ++i) {
        int ob = o0 + wid * 32 + i * 16 + quad * 4;   // 4 consecutive outs, same head
#pragma unroll
        for (int j = 0; j < 4; ++j) {
            int nG = n0 + j * 16 + low4;
            int b = nG >> 12, n = nG & 4095;
            f32x4 v = acc[i][j];
            if (ob < 128) {
                int head = ob >> 5, ch = ob & 31;
                unsigned long long d =
                    (unsigned long long)pk2bf(v[0] * QSCALE_LOG2E, v[1] * QSCALE_LOG2E) |
                    ((unsigned long long)pk2bf(v[2] * QSCALE_LOG2E, v[3] * QSCALE_LOG2E) << 32);
                *(unsigned long long*)(Q + ((size_t)(b * 4 + head) * NPOS + n) * 32 + ch) = d;
            } else if (ob < 256) {
                int o2 = ob - 128; int head = o2 >> 5, ch = o2 & 31;
                unsigned long long d =
                    (unsigned long long)pk2bf(v[0], v[1]) |
                    ((unsigned long long)pk2bf(v[2], v[3]) << 32);
                *(unsigned long long*)(K + ((size_t)(b * 4 + head) * NPOS + n) * 32 + ch) = d;
            } else {
#pragma unroll
                for (int r = 0; r < 4; ++r) {
                    int o2 = ob + r - 256; int head = o2 >> 5, ch = o2 & 31;
                    V[((size_t)((b * 4 + head) * 32 + ch)) * NPOS + n] = f2bf(v[r]);
                }
            }
        }
    }
}

// ---------------- kernel 4: attention, 32x32x16 MFMA + permlane P transform ----------------
// Grid: qt(32) x bh(16), blockIdx = qt*16 + bh (same-bh blocks share an XCD: 16 % 8 == 0).
// Block: 4 waves. wave (qg = wid&1, kh = wid>>1): 64 queries (qg half of the block's
// 128), 2048 keys (kh half). Per 64-key iter: K(4KB)+V(4KB) per key-half staged into
// dbuf LDS (frag order, lane*16). S^T = K.Q^T via 32x32x16 (C: col=query, row=key);
// exp2 -> packed bf16 pairs -> v_permlane32_swap rearranges C-layout packs directly
// into the PV B-operand fragments (NO LDS round-trip for P). O^T = V.P^T accumulated
// in C-layout. Key-halves combined through LDS at the end.
__global__ __launch_bounds__(256, 2) void k_attn(const unsigned short* __restrict__ Q,
                                                 const unsigned short* __restrict__ K,
                                                 const unsigned short* __restrict__ V,
                                                 unsigned short* __restrict__ attnO) {
    __shared__ __align__(16) unsigned char smem[2 * 16384];   // 32 KB KV dbuf (combine area reuses it)
    int bh = blockIdx.x & 15;
    int qt = blockIdx.x >> 4;          // 0..31
    int wid = threadIdx.x >> 6, lane = threadIdx.x & 63;
    int q5 = lane & 31, h = lane >> 5;
    int qg = wid & 1, kh = wid >> 1;
    int q0 = qt * 128 + qg * 64;
    int khk = kh * 2048;

    const unsigned short* Qp  = Q + (size_t)bh * NPOS * 32;
    const unsigned short* Kbh = K + (size_t)bh * NPOS * 32;
    const unsigned short* Vbh = V + (size_t)bh * 32 * NPOS;

    // Q B-frags [g][ch-chunk]: B[k=ch][n=q]; lane holds 8 ch for query q5 (+32h ch offset)
    s16x8 bq00 = *(const s16x8*)(Qp + (size_t)(q0 + q5) * 32 + h * 8);
    s16x8 bq01 = *(const s16x8*)(Qp + (size_t)(q0 + q5) * 32 + 16 + h * 8);
    s16x8 bq10 = *(const s16x8*)(Qp + (size_t)(q0 + 32 + q5) * 32 + h * 8);
    s16x8 bq11 = *(const s16x8*)(Qp + (size_t)(q0 + 32 + q5) * 32 + 16 + h * 8);

    // per-lane global staging sources
    const unsigned short* sK = Kbh + (size_t)q5 * 32 + h * 8;
    const unsigned short* sV = Vbh + (size_t)q5 * NPOS + h * 8;
    unsigned char* wbase0 = smem + kh * 8192;
    unsigned char* wbase1 = smem + 16384 + kh * 8192;

    auto stage = [&](int bufi, int k0) {
        unsigned char* wb = bufi ? wbase1 : wbase0;
        if (qg == 0) {   // K: tiles t=0,1; frags f=0,1 (1 KB each, lane*16 order)
            const unsigned short* p = sK + (size_t)k0 * 32;
            async_cp16(p,        wb);
            async_cp16(p + 16,   wb + 1024);
            async_cp16(p + 1024, wb + 2048);
            async_cp16(p + 1040, wb + 3072);
        } else {         // V: chunks c=0..3 (16 keys each)
            const unsigned short* p = sV + k0;
            async_cp16(p,      wb + 4096);
            async_cp16(p + 16, wb + 5120);
            async_cp16(p + 32, wb + 6144);
            async_cp16(p + 48, wb + 7168);
        }
    };

    f32x16 oT0 = {}, oT1 = {};
    float lsum0 = 0.0f, lsum1 = 0.0f;
    const int lby = lane * 16;

    stage(0, khk);
    __syncthreads();

#pragma unroll 1
    for (int it = 0; it < 32; ++it) {
        if (it + 1 < 32) stage((it + 1) & 1, khk + (it + 1) * 64);
        const unsigned char* kb = smem + (it & 1) * 16384 + kh * 8192;
#pragma unroll
        for (int t = 0; t < 2; ++t) {
            s16x8 ak0 = *(const s16x8*)(kb + t * 2048 + lby);
            s16x8 ak1 = *(const s16x8*)(kb + t * 2048 + 1024 + lby);
            f32x16 s0 = {}, s1 = {};
            s0 = MFMA32(ak0, bq00, s0); s0 = MFMA32(ak1, bq01, s0);
            s1 = MFMA32(ak0, bq10, s1); s1 = MFMA32(ak1, bq11, s1);
            unsigned p0[8], p1[8];
#pragma unroll
            for (int i = 0; i < 8; ++i) {
                float a0 = __builtin_amdgcn_exp2f(s0[2 * i]);
                float a1 = __builtin_amdgcn_exp2f(s0[2 * i + 1]);
                float b0 = __builtin_amdgcn_exp2f(s1[2 * i]);
                float b1 = __builtin_amdgcn_exp2f(s1[2 * i + 1]);
                lsum0 += a0 + a1;
                lsum1 += b0 + b1;
                p0[i] = pk2bf(a0, a1);
                p1[i] = pk2bf(b0, b1);
            }
            // C-layout -> B-operand fragment transform (pure VALU)
            plswap(p0[0], p0[2]); plswap(p0[1], p0[3]);
            plswap(p0[4], p0[6]); plswap(p0[5], p0[7]);
            plswap(p1[0], p1[2]); plswap(p1[1], p1[3]);
            plswap(p1[4], p1[6]); plswap(p1[5], p1[7]);
            s16x8 bp0lo = mk8(p0[0], p0[1], p0[2], p0[3]);
            s16x8 bp0hi = mk8(p0[4], p0[5], p0[6], p0[7]);
            s16x8 bp1lo = mk8(p1[0], p1[1], p1[2], p1[3]);
            s16x8 bp1hi = mk8(p1[4], p1[5], p1[6], p1[7]);

            s16x8 av0 = *(const s16x8*)(kb + 4096 + (2 * t) * 1024 + lby);
            s16x8 av1 = *(const s16x8*)(kb + 4096 + (2 * t + 1) * 1024 + lby);
            oT0 = MFMA32(av0, bp0lo, oT0); oT0 = MFMA32(av1, bp0hi, oT0);
            oT1 = MFMA32(av0, bp1lo, oT1); oT1 = MFMA32(av1, bp1hi, oT1);
        }
        __syncthreads();
    }

    // per-query lsum over this wave's key half (cols are lane&31; halves h hold disjoint rows)
    lsum0 += __shfl_xor(lsum0, 32);
    lsum1 += __shfl_xor(lsum1, 32);

    // combine key halves through LDS (kv buffers are dead now)
    float* area = (float*)smem + qg * 2176;   // 2048 floats O + 128 floats lsum
    if (kh) {
#pragma unroll
        for (int j = 0; j < 4; ++j) {
            *(f32x4*)(area + j * 256 + lane * 4) =
                f32x4{oT0[4 * j], oT0[4 * j + 1], oT0[4 * j + 2], oT0[4 * j + 3]};
            *(f32x4*)(area + 1024 + j * 256 + lane * 4) =
                f32x4{oT1[4 * j], oT1[4 * j + 1], oT1[4 * j + 2], oT1[4 * j + 3]};
        }
        area[2048 + lane * 2]     = lsum0;
        area[2048 + lane * 2 + 1] = lsum1;
    }
    __syncthreads();
    if (!kh) {
        lsum0 += area[2048 + lane * 2];
        lsum1 += area[2048 + lane * 2 + 1];
        float inv0 = 1.0f / lsum0, inv1 = 1.0f / lsum1;
        int b = bh >> 2, head = bh & 3;
        int n0 = q0 + q5, n1 = q0 + 32 + q5;
        unsigned short* base0 = attnO + ((size_t)(b * NPOS + n0)) * CHID + head * 32 + 4 * h;
        unsigned short* base1 = attnO + ((size_t)(b * NPOS + n1)) * CHID + head * 32 + 4 * h;
#pragma unroll
        for (int j = 0; j < 4; ++j) {
            f32x4 r0 = *(const f32x4*)(area + j * 256 + lane * 4);
            f32x4 r1 = *(const f32x4*)(area + 1024 + j * 256 + lane * 4);
            unsigned long long d0 =
                (unsigned long long)pk2bf((oT0[4 * j] + r0[0]) * inv0, (oT0[4 * j + 1] + r0[1]) * inv0) |
                ((unsigned long long)pk2bf((oT0[4 * j + 2] + r0[2]) * inv0, (oT0[4 * j + 3] + r0[3]) * inv0) << 32);
            *(unsigned long long*)(base0 + 8 * j) = d0;
            unsigned long long d1 =
                (unsigned long long)pk2bf((oT1[4 * j] + r1[0]) * inv1, (oT1[4 * j + 1] + r1[1]) * inv1) |
                ((unsigned long long)pk2bf((oT1[4 * j + 2] + r1[2]) * inv1, (oT1[4 * j + 3] + r1[3]) * inv1) << 32);
            *(unsigned long long*)(base1 + 8 * j) = d1;
        }
    }
}

// ---------------- kernel 5: output projection GEMM + bias, LDS-staged ----------------
__global__ __launch_bounds__(256, 4) void k_out(const unsigned short* __restrict__ wo,
                                                const unsigned short* __restrict__ attnO,
                                                const float* __restrict__ bias,
                                                float* __restrict__ out) {
    __shared__ __align__(16) unsigned char smem[2 * 12288];   // 24 KB
    int mt = blockIdx.x & 1;
    int nt = blockIdx.x >> 1;
    int wid = threadIdx.x >> 6, lane = threadIdx.x & 63;
    int quad = lane >> 4, low4 = lane & 15;
    int o0 = mt * 128, n0 = nt * 64;
    int lb = lane * 16;

    const unsigned short* srcA0 = wo + (size_t)(o0 + wid * 32 + low4) * CHID + quad * 8;
    const unsigned short* srcA1 = srcA0 + 16 * CHID;
    const unsigned short* srcB  = attnO + (size_t)(n0 + wid * 16 + low4) * CHID + quad * 8;
    int dA0 = wid * 2048, dA1 = dA0 + 1024, dB = 8192 + wid * 1024;

    async_cp16(srcA0, smem + dA0 + lb);
    async_cp16(srcA1, smem + dA1 + lb);
    async_cp16(srcB,  smem + dB  + lb);
    __syncthreads();

    f32x4 acc[2][4] = {};
    for (int c = 0; c < 4; ++c) {
        if (c < 3) {
            unsigned char* nxt = smem + ((c + 1) & 1) * 12288;
            async_cp16(srcA0 + (c + 1) * 32, nxt + dA0 + lb);
            async_cp16(srcA1 + (c + 1) * 32, nxt + dA1 + lb);
            async_cp16(srcB  + (c + 1) * 32, nxt + dB  + lb);
        }
        const unsigned char* cur = smem + (c & 1) * 12288;
        s16x8 a0 = *(const s16x8*)(cur + wid * 2048 + lb);
        s16x8 a1 = *(const s16x8*)(cur + wid * 2048 + 1024 + lb);
#pragma unroll
        for (int j = 0; j < 4; ++j) {
            s16x8 bj = *(const s16x8*)(cur + 8192 + j * 1024 + lb);
            acc[0][j] = __builtin_amdgcn_mfma_f32_16x16x32_bf16(a0, bj, acc[0][j], 0, 0, 0);
            acc[1][j] = __builtin_amdgcn_mfma_f32_16x16x32_bf16(a1, bj, acc[1][j], 0, 0, 0);
        }
        __syncthreads();
    }

#pragma unroll
    for (int i = 0; i < 2; ++i) {
        int ob = o0 + wid * 32 + i * 16 + quad * 4;
#pragma unroll
        for (int j = 0; j < 4; ++j) {
            int nG = n0 + j * 16 + low4;
            int b = nG >> 12, n = nG & 4095;
#pragma unroll
            for (int r = 0; r < 4; ++r) {
                int o = ob + r;
                out[((size_t)(b * CIN + o)) * NPOS + n] = acc[i][j][r] + bias[o];
            }
        }
    }
}

extern "C" void kernel_launch(void* const* d_in, const int* in_sizes, int n_in,
                              void* d_out, int out_size, void* d_ws, size_t ws_size,
                              hipStream_t stream) {
    const float* x    = (const float*)d_in[0];
    const float* wqkv = (const float*)d_in[1];
    const float* wout = (const float*)d_in[2];
    const float* bout = (const float*)d_in[3];
    float* out = (float*)d_out;

    unsigned short* Q       = (unsigned short*)d_ws;
    unsigned short* K       = Q + (size_t)BH * NPOS * 32;       // +4 MB
    unsigned short* V       = K + (size_t)BH * NPOS * 32;       // +4 MB
    unsigned short* attnO   = V + (size_t)BH * 32 * NPOS;       // +4 MB
    unsigned short* xT      = attnO + (size_t)NTOT * CHID;      // +4 MB
    unsigned short* wqkv_bf = xT + (size_t)NTOT * CIN;          // +8 MB
    unsigned short* wout_bf = wqkv_bf + QKV_O * CIN;            // +192 KB

    k_convert_w<<<(QKV_O * CIN + 255) / 256, 256, 0, stream>>>(wqkv, wout, wqkv_bf, wout_bf);
    k_transpose_x<<<NB * (CIN / 32) * (NPOS / 32), 256, 0, stream>>>(x, xT);
    k_qkv<<<3 * (NTOT / 64), 256, 0, stream>>>(wqkv_bf, xT, Q, K, V);
    k_attn<<<(NPOS / 128) * BH, 256, 0, stream>>>(Q, K, V, attnO);
    k_out<<<2 * (NTOT / 64), 256, 0, stream>>>(wout_bf, attnO, bout, out);
}